// Round 1
// baseline (880.208 us; speedup 1.0000x reference)
//
#include <hip/hip_runtime.h>

#define NTOK 64
#define NHEADS 8
#define HD 32
#define DIMC 256
#define BATCH 2048

typedef _Float16 f16x8 __attribute__((ext_vector_type(8)));
typedef unsigned short u16x8 __attribute__((ext_vector_type(8)));
typedef float f32x4 __attribute__((ext_vector_type(4)));

static __device__ __forceinline__ unsigned short f2h(float x) {
  _Float16 h = (_Float16)x;  // v_cvt_f16_f32, RNE
  return __builtin_bit_cast(unsigned short, h);
}

// ---------------- bias MLP: rel_pos[64*64,2] -> bias[8][64*64] ----------------
__global__ __launch_bounds__(256) void bias_mlp(const float* __restrict__ rel_pos,
                                                const float* __restrict__ w1,
                                                const float* __restrict__ b1,
                                                const float* __restrict__ w2,
                                                const float* __restrict__ b2,
                                                float* __restrict__ bias_out) {
  int p = blockIdx.x * 256 + threadIdx.x;  // 0..4095
  float r0 = rel_pos[p * 2 + 0];
  float r1 = rel_pos[p * 2 + 1];
  float acc[NHEADS];
#pragma unroll
  for (int hh = 0; hh < NHEADS; ++hh) acc[hh] = b2[hh];
  for (int j = 0; j < 256; ++j) {
    float hv = fmaf(r0, w1[j], fmaf(r1, w1[256 + j], b1[j]));
    hv = fmaxf(hv, 0.0f);
#pragma unroll
    for (int hh = 0; hh < NHEADS; ++hh)
      acc[hh] = fmaf(hv, w2[j * NHEADS + hh], acc[hh]);
  }
#pragma unroll
  for (int hh = 0; hh < NHEADS; ++hh)
    bias_out[hh * (NTOK * NTOK) + p] = acc[hh];
}

// ---------------- fused window attention, one block per (branch,b,h) ----------
__global__ __launch_bounds__(256) void win_attn(const float* __restrict__ qkv,
                                                const float* __restrict__ ass_qkv,
                                                const float* __restrict__ bias,
                                                float* __restrict__ out) {
  const int bh = blockIdx.x;       // 0..16383
  const int branch = blockIdx.y;   // 0,1
  const int b = bh >> 3;
  const int h = bh & 7;
  const float* __restrict__ src = branch ? ass_qkv : qkv;
  float* __restrict__ dst = out + (size_t)branch * ((size_t)BATCH * NTOK * DIMC);

  // fp16 tiles. Vs padded to 34 (68B rows) so the strided PV B-frag reads
  // (stride 34 u16) put the 4 quads on distinct banks. Ps padded to 72
  // (144B rows, 16B-aligned) for b128 A-frag reads.
  __shared__ __align__(16) unsigned short Qs[NTOK][32];
  __shared__ __align__(16) unsigned short Ks[NTOK][32];
  __shared__ __align__(16) unsigned short Vs[NTOK][34];
  __shared__ __align__(16) unsigned short Ps[4][16][72];

  const int t = threadIdx.x;
  const size_t base = (size_t)b * (NTOK * 3 * DIMC);

  // stage 6144 floats (Q,K,V slices of this head) -> fp16 LDS; 6 float4/thread
#pragma unroll
  for (int k = 0; k < 6; ++k) {
    int idx = t + k * 256;       // 0..1535 float4s
    int comp = idx >> 9;         // 0=q 1=k 2=v (512 float4 each)
    int rem = idx & 511;
    int n = rem >> 3;            // token
    int d4 = rem & 7;            // float4 within 32 dims
    const float4 v = *reinterpret_cast<const float4*>(
        src + base + (size_t)n * 768 + comp * 256 + h * 32 + d4 * 4);
    unsigned lo = (unsigned)f2h(v.x) | ((unsigned)f2h(v.y) << 16);
    unsigned hi = (unsigned)f2h(v.z) | ((unsigned)f2h(v.w) << 16);
    unsigned* p;
    if (comp == 0)      p = reinterpret_cast<unsigned*>(&Qs[n][d4 * 4]);
    else if (comp == 1) p = reinterpret_cast<unsigned*>(&Ks[n][d4 * 4]);
    else                p = reinterpret_cast<unsigned*>(&Vs[n][d4 * 4]);
    p[0] = lo;
    p[1] = hi;
  }
  __syncthreads();

  const int lane = t & 63;
  const int wv = t >> 6;        // wave id: owns query rows [wv*16, wv*16+16)
  const int quad = lane >> 4;
  const int l15 = lane & 15;

  // ---- S = Q K^T (rows wv*16..+15, all 64 cols) : 4 MFMAs ----
  // A[m=l15][k=quad*8+j] ; B[k=quad*8+j][n=l15] = K[n][k]
  f16x8 aq = *reinterpret_cast<const f16x8*>(&Qs[wv * 16 + l15][quad * 8]);
  f32x4 sfrag[4];
#pragma unroll
  for (int ct = 0; ct < 4; ++ct) {
    f16x8 bk = *reinterpret_cast<const f16x8*>(&Ks[ct * 16 + l15][quad * 8]);
    f32x4 z = {0.f, 0.f, 0.f, 0.f};
    sfrag[ct] = __builtin_amdgcn_mfma_f32_16x16x32_f16(aq, bk, z, 0, 0, 0);
  }

  // ---- scale + bias + softmax (C-layout: row=quad*4+r, col=ct*16+l15) ----
  const float scale = 0.17677669529663688f;  // 32^-0.5
  const float* bptr = bias + h * 4096 + (wv * 16 + quad * 4) * 64 + l15;
  float s[4][4];
#pragma unroll
  for (int ct = 0; ct < 4; ++ct)
#pragma unroll
    for (int r = 0; r < 4; ++r)
      s[ct][r] = fmaf(sfrag[ct][r], scale, bptr[r * 64 + ct * 16]);

#pragma unroll
  for (int r = 0; r < 4; ++r) {
    float m = fmaxf(fmaxf(s[0][r], s[1][r]), fmaxf(s[2][r], s[3][r]));
    m = fmaxf(m, __shfl_xor(m, 1));
    m = fmaxf(m, __shfl_xor(m, 2));
    m = fmaxf(m, __shfl_xor(m, 4));
    m = fmaxf(m, __shfl_xor(m, 8));
    float l = 0.f;
#pragma unroll
    for (int ct = 0; ct < 4; ++ct) {
      s[ct][r] = __expf(s[ct][r] - m);
      l += s[ct][r];
    }
    l += __shfl_xor(l, 1);
    l += __shfl_xor(l, 2);
    l += __shfl_xor(l, 4);
    l += __shfl_xor(l, 8);
    float inv = 1.0f / l;
#pragma unroll
    for (int ct = 0; ct < 4; ++ct)
      Ps[wv][quad * 4 + r][ct * 16 + l15] = f2h(s[ct][r] * inv);
  }
  __syncthreads();  // intra-wave dependency only, kept for safety

  // ---- O = P V : P[16x64] x V[64x32], 2 k-steps x 2 col-tiles ----
  f32x4 of[2] = {{0.f, 0.f, 0.f, 0.f}, {0.f, 0.f, 0.f, 0.f}};
#pragma unroll
  for (int ks = 0; ks < 2; ++ks) {
    f16x8 pa = *reinterpret_cast<const f16x8*>(&Ps[wv][l15][ks * 32 + quad * 8]);
#pragma unroll
    for (int ct = 0; ct < 2; ++ct) {
      u16x8 bu;
#pragma unroll
      for (int j = 0; j < 8; ++j)
        bu[j] = Vs[ks * 32 + quad * 8 + j][ct * 16 + l15];
      f16x8 vb = __builtin_bit_cast(f16x8, bu);
      of[ct] = __builtin_amdgcn_mfma_f32_16x16x32_f16(pa, vb, of[ct], 0, 0, 0);
    }
  }

  // ---- write O (C-layout): row = wv*16+quad*4+r, col = ct*16+l15 ----
  float* op = dst + (size_t)b * (NTOK * DIMC) +
              (size_t)(wv * 16 + quad * 4) * DIMC + h * 32 + l15;
#pragma unroll
  for (int ct = 0; ct < 2; ++ct)
#pragma unroll
    for (int r = 0; r < 4; ++r)
      op[r * 256 + ct * 16] = of[ct][r];
}

extern "C" void kernel_launch(void* const* d_in, const int* in_sizes, int n_in,
                              void* d_out, int out_size, void* d_ws, size_t ws_size,
                              hipStream_t stream) {
  const float* qkv     = (const float*)d_in[0];
  const float* ass_qkv = (const float*)d_in[1];
  const float* rel_pos = (const float*)d_in[2];
  const float* w1      = (const float*)d_in[3];
  const float* b1      = (const float*)d_in[4];
  const float* w2      = (const float*)d_in[5];
  const float* b2      = (const float*)d_in[6];
  float* out = (float*)d_out;
  float* bias_ws = (float*)d_ws;  // 8*4096 floats = 128 KiB

  bias_mlp<<<dim3(16), dim3(256), 0, stream>>>(rel_pos, w1, b1, w2, b2, bias_ws);
  win_attn<<<dim3(BATCH * NHEADS, 2), dim3(256), 0, stream>>>(qkv, ass_qkv, bias_ws, out);
}